// Round 20
// baseline (57.884 us; speedup 1.0000x reference)
//
#include <hip/hip_runtime.h>
#include <hip/hip_bf16.h>

// B=32, T=256, N=1024 -> R = 8192 rows, K = 1023 (padded 1024)
// alpha=0.5, b[m] = 1/(sqrt(m+1)+sqrt(m)), coef = sqrt(1023)/Gamma(1.5)
#define COEF 36.090511f
#define INV_COUNT (1.0f / 8388608.0f)   // 1 / (32*256*1024)

typedef __attribute__((ext_vector_type(4))) float f32x4;
typedef __attribute__((ext_vector_type(2))) unsigned long long u64x2;

typedef const __attribute__((address_space(1))) unsigned int* gas_ptr;
typedef __attribute__((address_space(3))) unsigned int* las_ptr;

__device__ __forceinline__ void load_lds16(const void* g, void* l) {
  __builtin_amdgcn_global_load_lds((gas_ptr)g, (las_ptr)l, 16, 0, 0);
}

// manual OCP e4m3fn decode (bias 7): exact
__device__ __forceinline__ float fp8_dec(unsigned int v) {
  const unsigned e = (v >> 3) & 0xF, m = v & 7;
  const int mant = e ? (8 + (int)m) : (int)m;
  const int ee = e ? (int)e : 1;
  float f = (float)mant * __int_as_float((ee + 117) << 23);  // mant * 2^(ee-10)
  return (v & 0x80) ? -f : f;
}

// Mt8d build: 8 dedup'd Toeplitz tiles [d][i'][j'] = fp8(b[d*128+i'-j']), 128KB total.
__global__ void mtb(unsigned char* __restrict__ Mt8d) {
  const int g = blockIdx.x * 1024 + threadIdx.x * 4;
  const int d = g >> 14;
  const int rem = g & 16383;
  const int ip = rem >> 7;
  const int j0 = rem & 127;
  float v[4];
#pragma unroll
  for (int e = 0; e < 4; e++) {
    int m = d * 128 + ip - (j0 + e);
    v[e] = 0.f;
    if (m >= 0) { float fm_ = (float)m; v[e] = 1.0f / (sqrtf(fm_ + 1.f) + sqrtf(fm_)); }
  }
  int w_ = __builtin_amdgcn_cvt_pk_fp8_f32(v[0], v[1], 0, false);
  w_ = __builtin_amdgcn_cvt_pk_fp8_f32(v[2], v[3], w_, true);
  *(unsigned int*)(Mt8d + g) = (unsigned int)w_;
}

// FUSED prep+gemm with PIPELINED A-recompute (T14 split): ldA issues u_pred loads one
// full iteration ahead; packA consumes them (no exposed latency) after the next barrier.
// 64x128 tile, BK=128, 8 waves (32x32), 1024 blocks, 32KB LDS -> 4 blocks/CU.
__launch_bounds__(512, 8)
__global__ void gemm(const float* __restrict__ up, const float* __restrict__ utr,
                     const unsigned char* __restrict__ Mt8d,
                     float* __restrict__ gpart) {
  __shared__ unsigned char sA[2][8192];    // [64 rows][128 k], quad-swizzled du (fp8)
  __shared__ unsigned char sB[16384];      // [128 cols][128 k], single-buffered
  __shared__ float wsum[8], wsumD[8];

  const int t = threadIdx.x;      // 512 threads = 8 waves
  const int w = t >> 6;
  const int lane = t & 63;

  const int bid = blockIdx.x;      // 0..1023
  const int xcd = bid & 7;
  const int local = bid >> 3;      // 0..127
  const int e = local & 1;
  const int j = local >> 1;        // 0..63
  const int h = (j < 32) ? (j & 7) : 7 - (j & 7);
  const int cb = e ? 7 - h : h;
  const int r16 = (((j >> 3) & 3) << 2) | (((j >> 5) & 1) << 1) | e;   // bijective
  const int rb = xcd * 16 + r16;   // XCD x owns rows [x*1024, +1024)
  const int row0 = rb * 64;
  const int col0 = cb * 128;
  const int nkb = cb + 1;          // K-blocks of 128 (triangular skip)

  const f32x4 vzero = {0.f, 0.f, 0.f, 0.f};
  f32x4 acc[2][2];
#pragma unroll
  for (int i = 0; i < 2; i++)
#pragma unroll
    for (int jj = 0; jj < 2; jj++) acc[i][jj] = vzero;

  // staging geometry: thread t -> (srow = t>>3, phys quad = t&7); src quad = phys^(srow&7)
  const int srow = t >> 3;                            // 0..63
  const int sq = ((t & 7) ^ (srow & 7)) * 16;         // pre-swizzled du-col window
  const float* uprow = up + (size_t)(row0 + srow) * 1024;
  const unsigned char* gB0 = Mt8d + srow * 128 + sq;

  // T14 split: ldA issues the 5 loads (4x f32x4 + edge scalar); packA consumes a full
  // iteration later (diff -> cvt_pk fp8 -> one ds_write_b128). regs: ~17 VGPR.
  f32x4 v0, v1, v2, v3; float u16; int gc0cur;
  auto ldA = [&](int kb) {
    const int gc0 = kb * 128 + sq;
    const float* rp = uprow + gc0;
    v0 = *(const f32x4*)(rp);
    v1 = *(const f32x4*)(rp + 4);
    v2 = *(const f32x4*)(rp + 8);
    v3 = *(const f32x4*)(rp + 12);
    u16 = (gc0 < 1008) ? rp[16] : 0.f;
    gc0cur = gc0;
  };
  auto packA = [&](int buf) {
    float d_[16];
    d_[0]=v0[1]-v0[0]; d_[1]=v0[2]-v0[1]; d_[2]=v0[3]-v0[2]; d_[3]=v1[0]-v0[3];
    d_[4]=v1[1]-v1[0]; d_[5]=v1[2]-v1[1]; d_[6]=v1[3]-v1[2]; d_[7]=v2[0]-v1[3];
    d_[8]=v2[1]-v2[0]; d_[9]=v2[2]-v2[1]; d_[10]=v2[3]-v2[2]; d_[11]=v3[0]-v2[3];
    d_[12]=v3[1]-v3[0]; d_[13]=v3[2]-v3[1]; d_[14]=v3[3]-v3[2]; d_[15]=u16-v3[3];
    if (gc0cur == 1008) d_[15] = 0.f;      // du[1023] = 0 pad
    unsigned int pk[4];
#pragma unroll
    for (int q = 0; q < 4; q++) {
      int w_ = __builtin_amdgcn_cvt_pk_fp8_f32(d_[q*4+0], d_[q*4+1], 0, false);
      w_ = __builtin_amdgcn_cvt_pk_fp8_f32(d_[q*4+2], d_[q*4+3], w_, true);
      pk[q] = (unsigned int)w_;
    }
    *(u64x2*)&sA[buf][t * 16] = *(u64x2*)pk;
  };

  auto stageB = [&](int kb) {              // 2 global_load_lds (16KB tile, d = cb-kb)
    const size_t doff = (size_t)(cb - kb) * 16384;
#pragma unroll
    for (int l = 0; l < 2; l++)
      load_lds16(gB0 + doff + l * 64 * 128, (void*)&sB[l * 8192 + t * 16]);
  };

  const int wm = w >> 2, wn = w & 3;       // wave tile: rows wm*32, cols wn*32
  const int frow = lane & 15;
  const int g4 = lane >> 4;

  auto compute = [&](int buf) {
#pragma unroll
    for (int p = 0; p < 2; p++) {
      const int lq = g4 * 2 + p;
      const int ph = lq ^ (frow & 7);
      u64x2 aV[2], bV[2];
#pragma unroll
      for (int fm = 0; fm < 2; fm++)
        aV[fm] = *(const u64x2*)&sA[buf][(wm * 32 + fm * 16 + frow) * 128 + ph * 16];
#pragma unroll
      for (int fn = 0; fn < 2; fn++)
        bV[fn] = *(const u64x2*)&sB[(wn * 32 + fn * 16 + frow) * 128 + ph * 16];
#pragma unroll
      for (int fm = 0; fm < 2; fm++)
#pragma unroll
        for (int fn = 0; fn < 2; fn++) {
          acc[fm][fn] = __builtin_amdgcn_mfma_f32_16x16x32_fp8_fp8(
              (long long)aV[fm].x, (long long)bV[fn].x, acc[fm][fn], 0, 0, 0);
          acc[fm][fn] = __builtin_amdgcn_mfma_f32_16x16x32_fp8_fp8(
              (long long)aV[fm].y, (long long)bV[fn].y, acc[fm][fn], 0, 0, 0);
        }
    }
  };

  // prologue: A(0) load+pack (one exposed wait, once), then issue A(1)
  ldA(0);
  packA(0);                                // sA[0] <- du tile 0
  if (nkb > 1) ldA(1);
  for (int kb = 0; kb < nkb; kb++) {
    // BARRIER A: compute(kb-1) done -> sB free; sA[(kb+1)&1] free to overwrite
    asm volatile("" ::: "memory");
    __builtin_amdgcn_s_barrier();
    asm volatile("" ::: "memory");
    if (kb + 1 < nkb) packA((kb + 1) & 1);             // regs landed a full iter ago
    stageB(kb);                                        // issue B(kb): 2 lds-direct loads
    if (kb + 2 < nkb) {
      ldA(kb + 2);                                     // issue A(kb+2): 5 loads in flight
      asm volatile("s_waitcnt vmcnt(5)" ::: "memory"); // drains B(kb); A-loads stay pending
    } else {
      asm volatile("s_waitcnt vmcnt(0)" ::: "memory"); // tail: drain B(kb)
    }
    asm volatile("s_waitcnt lgkmcnt(0)" ::: "memory"); // own ds_writes complete
    // BARRIER B: tile kb fully resident
    __builtin_amdgcn_s_barrier();
    asm volatile("" ::: "memory");
    compute(kb & 1);
  }

  // fused epilogue: C/D layout col = lane&15, row = (lane>>4)*4 + reg  [HW-verified].
  // du bytes from LAST A-tile in LDS: byte (rt,c) at rt*128 + ((c>>4)^(rt&7))*16 + (c&15).
  // Neighbor (c+1) via __shfl_down; frow==15: LDS (c<127) or recompute from u_pred (c==127).
  const int lastBuf = (nkb - 1) & 1;
  float psum = 0.f;
#pragma unroll
  for (int fm = 0; fm < 2; fm++) {
#pragma unroll
    for (int fn = 0; fn < 2; fn++) {
      const int c = wn * 32 + fn * 16 + frow;
      const int icol = col0 + c;                 // du index i; output position n = i+1
#pragma unroll
      for (int reg = 0; reg < 4; reg++) {
        const int rt = wm * 32 + fm * 16 + g4 * 4 + reg;
        float dui = fp8_dec(sA[lastBuf][rt * 128 + (((c >> 4) ^ (rt & 7)) << 4) + (c & 15)]);
        float dnext = __shfl_down(dui, 1, 64);
        if (frow == 15) {
          if (c == 127) {                        // tile edge: recompute du[icol+1] from u_pred
            if (icol < 1022) {
              const float* rr = up + (size_t)(row0 + rt) * 1024 + icol + 1;
              dnext = rr[1] - rr[0];
            } else dnext = 0.f;
          } else {
            const int c1 = c + 1;
            dnext = fp8_dec(sA[lastBuf][rt * 128 + (((c1 >> 4) ^ (rt & 7)) << 4) + (c1 & 15)]);
          }
        }
        if (icol < 1023) {
          float frac = COEF * acc[fm][fn][reg];
          float ut = (icol == 1022) ? dui : 0.5f * (dui + dnext);
          float res = ut - frac;
          psum += res * res;
        }
      }
    }
  }

  // cb==0 block extras (least K-work): n=0 physics terms + data-loss for its 64 rows
  float dsum = 0.f;
  if (cb == 0) {
    if (t < 64) {                                // du[rt,0]^2 from sA[0] (tile kb=0)
      float d0 = fp8_dec(sA[lastBuf][t * 128 + ((t & 7) << 4)]);
      psum += d0 * d0;
    }
    const float* upr = up + (size_t)(row0 + (t >> 3)) * 1024 + (t & 7) * 4;
    const float* utr_ = utr + (size_t)(row0 + (t >> 3)) * 1024 + (t & 7) * 4;
#pragma unroll 4
    for (int i = 0; i < 32; i++) {               // 64 rows x 1024 cols, coalesced
      f32x4 a4 = *(const f32x4*)(upr + i * 32);
      f32x4 b4 = *(const f32x4*)(utr_ + i * 32);
      float e0 = a4[0]-b4[0], e1 = a4[1]-b4[1], e2 = a4[2]-b4[2], e3 = a4[3]-b4[3];
      dsum += e0*e0 + e1*e1 + e2*e2 + e3*e3;
    }
  }

#pragma unroll
  for (int off = 32; off > 0; off >>= 1) {
    psum += __shfl_down(psum, off, 64);
    dsum += __shfl_down(dsum, off, 64);
  }
  if (lane == 0) { wsum[w] = psum; wsumD[w] = dsum; }
  __syncthreads();
  if (t == 0) {
    float s = 0.f, sd = 0.f;
#pragma unroll
    for (int i = 0; i < 8; i++) { s += wsum[i]; sd += wsumD[i]; }
    gpart[bid] = s;
    gpart[1024 + bid] = sd;    // 0 for cb != 0
  }
}

// Single-block reduction of 2048 partials -> 3 outputs.
__global__ void finalize(const float* __restrict__ gpart, float* __restrict__ out) {
  const int t = threadIdx.x;    // 256 threads
  float ds = 0.f, ps = 0.f;
  for (int i = t; i < 1024; i += 256) { ps += gpart[i]; ds += gpart[1024 + i]; }

#pragma unroll
  for (int off = 32; off > 0; off >>= 1) {
    ds += __shfl_down(ds, off, 64);
    ps += __shfl_down(ps, off, 64);
  }
  __shared__ float sd[4], sp[4];
  const int lane = t & 63, w = t >> 6;
  if (lane == 0) { sd[w] = ds; sp[w] = ps; }
  __syncthreads();
  if (t == 0) {
    float data = (sd[0] + sd[1] + sd[2] + sd[3]) * INV_COUNT;
    float phys = (sp[0] + sp[1] + sp[2] + sp[3]) * INV_COUNT;
    out[0] = data + 0.1f * phys;
    out[1] = data;
    out[2] = phys;
  }
}

extern "C" void kernel_launch(void* const* d_in, const int* in_sizes, int n_in,
                              void* d_out, int out_size, void* d_ws, size_t ws_size,
                              hipStream_t stream) {
  const float* u_pred = (const float*)d_in[0];
  const float* u_true = (const float*)d_in[1];
  float* out = (float*)d_out;

  char* ws = (char*)d_ws;
  float* gpart = (float*)ws;                                    // 2048 floats (8 KiB)
  unsigned char* Mt8d = (unsigned char*)(ws + 131072);          // 8 tiles * 16 KiB = 128 KiB

  mtb<<<128, 256, 0, stream>>>(Mt8d);
  gemm<<<1024, 512, 0, stream>>>(u_pred, u_true, Mt8d, gpart);
  finalize<<<1, 256, 0, stream>>>(gpart, out);
}

// Round 21
// 44.954 us; speedup vs baseline: 1.2876x; 1.2876x over previous
//
#include <hip/hip_runtime.h>
#include <hip/hip_bf16.h>

// B=32, T=256, N=1024 -> R = 8192 rows, K = 1023 (padded 1024)
// alpha=0.5, b[m] = 1/(sqrt(m+1)+sqrt(m)), coef = sqrt(1023)/Gamma(1.5)
#define COEF 36.090511f
#define INV_COUNT (1.0f / 8388608.0f)   // 1 / (32*256*1024)

typedef __attribute__((ext_vector_type(4))) float f32x4;
typedef __attribute__((ext_vector_type(2))) unsigned long long u64x2;

typedef const __attribute__((address_space(1))) unsigned int* gas_ptr;
typedef __attribute__((address_space(3))) unsigned int* las_ptr;

__device__ __forceinline__ void load_lds16(const void* g, void* l) {
  __builtin_amdgcn_global_load_lds((gas_ptr)g, (las_ptr)l, 16, 0, 0);
}

// manual OCP e4m3fn decode (bias 7): exact
__device__ __forceinline__ float fp8_dec(unsigned int v) {
  const unsigned e = (v >> 3) & 0xF, m = v & 7;
  const int mant = e ? (8 + (int)m) : (int)m;
  const int ee = e ? (int)e : 1;
  float f = (float)mant * __int_as_float((ee + 117) << 23);  // mant * 2^(ee-10)
  return (v & 0x80) ? -f : f;
}

// prep blocks 0..8191: du8 rows, XCD-aligned map r = (b&7)*1024 + (b>>3).
// blocks 8192..8319: Mt8d = dedup'd Toeplitz B (8 tiles of 16KB, d-index).
__global__ void prep(const float* __restrict__ up, const float* __restrict__ utr,
                     unsigned char* __restrict__ du8, unsigned char* __restrict__ Mt8d,
                     float* __restrict__ dpart, float* __restrict__ ppart) {
  const int t = threadIdx.x;      // 256 threads
  if (blockIdx.x >= 8192) {
    const int g = (blockIdx.x - 8192) * 1024 + t * 4;   // byte index into 128KB tile set
    const int d = g >> 14;            // tile 0..7
    const int rem = g & 16383;
    const int ip = rem >> 7;          // i' 0..127
    const int j0 = rem & 127;         // j' byte
    float v[4];
#pragma unroll
    for (int e = 0; e < 4; e++) {
      int m = d * 128 + ip - (j0 + e);
      v[e] = 0.f;
      if (m >= 0) { float fm_ = (float)m; v[e] = 1.0f / (sqrtf(fm_ + 1.f) + sqrtf(fm_)); }
    }
    int w_ = __builtin_amdgcn_cvt_pk_fp8_f32(v[0], v[1], 0, false);
    w_ = __builtin_amdgcn_cvt_pk_fp8_f32(v[2], v[3], w_, true);
    *(unsigned int*)(Mt8d + g) = (unsigned int)w_;
    return;
  }

  const int r = ((blockIdx.x & 7) << 10) | (blockIdx.x >> 3);   // XCD-aligned row
  const int j0 = t * 4;
  const float* rowp = up + (size_t)r * 1024;

  f32x4 a = *(const f32x4*)(rowp + j0);
  f32x4 b = *(const f32x4*)(utr + (size_t)r * 1024 + j0);

  float a4 = __shfl_down(a[0], 1, 64);
  if ((t & 63) == 63 && t < 255) a4 = rowp[j0 + 4];

  float d0 = a[1] - a[0];
  float d1 = a[2] - a[1];
  float d2 = a[3] - a[2];
  float d3 = (t < 255) ? (a4 - a[3]) : 0.f;   // du[1023] = 0 pad

  int w_ = __builtin_amdgcn_cvt_pk_fp8_f32(d0, d1, 0, false);
  w_ = __builtin_amdgcn_cvt_pk_fp8_f32(d2, d3, w_, true);
  *(unsigned int*)(du8 + (size_t)r * 1024 + j0) = (unsigned int)w_;

  float e0 = a[0] - b[0], e1 = a[1] - b[1], e2 = a[2] - b[2], e3 = a[3] - b[3];
  float dsum = e0 * e0 + e1 * e1 + e2 * e2 + e3 * e3;

#pragma unroll
  for (int off = 32; off > 0; off >>= 1) dsum += __shfl_down(dsum, off, 64);
  __shared__ float ws4[4];
  const int lane = t & 63, w = t >> 6;
  if (lane == 0) ws4[w] = dsum;
  __syncthreads();
  if (t == 0) {
    dpart[r] = ws4[0] + ws4[1] + ws4[2] + ws4[3];
    ppart[r] = d0 * d0;   // physics residual at n=0: u_t = du[r,0], frac_lap[0] = 0
  }
}

// Y[r,i] = sum_j du[r,j] * b[i-j]; fused epilogue: resid = u_t - COEF*Y, psum += resid^2.
// UNIFORM-WORK fp8 GEMM: each block owns rows [row0,row0+64) and TWO 64-wide column
// tiles ct1 = p, ct2 = 15-p, processed in ONE 9-iteration K-loop (nkb(ct1)+nkb(ct2) = 9
// for every block -> zero dispatch-dependent imbalance). 8 waves (16x32 wave tile),
// 1024 blocks, 24KB LDS -> 4 blocks/CU = 32 waves/CU. sA dbuf; sB single 8KB (1 load).
__launch_bounds__(512, 8)
__global__ void gemm(const unsigned char* __restrict__ du8,
                     const unsigned char* __restrict__ Mt8d,
                     float* __restrict__ gpart,
                     const float* __restrict__ dpart, const float* __restrict__ ppart) {
  __shared__ unsigned char sA[2][8192];    // [64 rows][128 k], quad-swizzled du (fp8)
  __shared__ unsigned char sB[8192];       // [64 cols][128 k], single-buffered
  __shared__ float wsum[8];

  const int t = threadIdx.x;      // 512 threads = 8 waves
  const int w = t >> 6;
  const int lane = t & 63;

  const int bid = blockIdx.x;      // 0..1023
  const int xcd = bid & 7;
  const int local = bid >> 3;      // 0..127
  const int p = local & 7;
  const int r16 = local >> 3;      // 0..15
  const int rb = xcd * 16 + r16;   // XCD x owns rows [x*1024, +1024)
  const int row0 = rb * 64;
  const int ct1 = p, ct2 = 15 - p;
  const int nkb1 = (ct1 >> 1) + 1;           // iters in phase 1; total always 9

  const f32x4 vzero = {0.f, 0.f, 0.f, 0.f};
  f32x4 acc[2];
  acc[0] = vzero; acc[1] = vzero;

  // staging geometry: thread t -> (srow = t>>3, phys quad = t&7); src quad = phys^(srow&7)
  const int srow = t >> 3;                            // 0..63
  const int sq = ((t & 7) ^ (srow & 7)) * 16;         // pre-swizzled source byte col
  const unsigned char* gA0 = du8 + (size_t)(row0 + srow) * 1024 + sq;
  const unsigned char* gB0 = Mt8d + srow * 128 + sq;

  auto stageA = [&](int buf, int kb) {                // 1 load: 64x128 = 8KB
    load_lds16(gA0 + kb * 128, (void*)&sA[buf][t * 16]);
  };
  // B-tile (ct, kb): cols [ct*64,+64), k [kb*128,+128). Dedup: d = (ct>>1)-kb,
  // source row i' = (ct&1)*64 + srow  -> byte offset d*16384 + (ct&1)*8192.
  auto stageB = [&](int ct, int kb) {                 // 1 load: 64x128 = 8KB
    const size_t off = (size_t)((ct >> 1) - kb) * 16384 + (size_t)(ct & 1) * 8192;
    load_lds16(gB0 + off, (void*)&sB[t * 16]);
  };

  const int wm = w >> 1, wn = w & 1;     // wave tile: rows wm*16, cols wn*32
  const int frow = lane & 15;
  const int g4 = lane >> 4;

  auto compute = [&](int buf) {
#pragma unroll
    for (int p2 = 0; p2 < 2; p2++) {
      const int lq = g4 * 2 + p2;
      const int ph = lq ^ (frow & 7);
      u64x2 aV = *(const u64x2*)&sA[buf][(wm * 16 + frow) * 128 + ph * 16];
      u64x2 bV[2];
#pragma unroll
      for (int fn = 0; fn < 2; fn++)
        bV[fn] = *(const u64x2*)&sB[(wn * 32 + fn * 16 + frow) * 128 + ph * 16];
#pragma unroll
      for (int fn = 0; fn < 2; fn++) {
        acc[fn] = __builtin_amdgcn_mfma_f32_16x16x32_fp8_fp8(
            (long long)aV.x, (long long)bV[fn].x, acc[fn], 0, 0, 0);
        acc[fn] = __builtin_amdgcn_mfma_f32_16x16x32_fp8_fp8(
            (long long)aV.y, (long long)bV[fn].y, acc[fn], 0, 0, 0);
      }
    }
  };

  float psum = 0.f;
  // fused epilogue for one phase: C/D layout col = lane&15, row = (lane>>4)*4 + reg.
  // du from that phase's LAST A-tile in LDS; in-tile k-byte ck = (ct&1)*64 + c.
  // Neighbor via __shfl_down; frow==15 reads LDS (ck+1 in-tile) or global (ct odd, c==63).
  auto epilogue = [&](int ct, int lastBuf) {
#pragma unroll
    for (int fn = 0; fn < 2; fn++) {
      const int c = wn * 32 + fn * 16 + frow;    // col within 64-wide tile
      const int icol = ct * 64 + c;              // du index i; output position n = i+1
      const int ck = (ct & 1) * 64 + c;          // k-byte within the A-tile
#pragma unroll
      for (int reg = 0; reg < 4; reg++) {
        const int rt = wm * 16 + g4 * 4 + reg;   // row within tile (0..63)
        float dui = fp8_dec(sA[lastBuf][rt * 128 + (((ck >> 4) ^ (rt & 7)) << 4) + (ck & 15)]);
        float dnext = __shfl_down(dui, 1, 64);   // dui of (rt, c+1) for frow<15
        if (frow == 15) {
          if (c == 63 && (ct & 1)) {             // tile edge at odd ct: global byte
            dnext = (icol < 1022) ? fp8_dec(du8[(size_t)(row0 + rt) * 1024 + icol + 1]) : 0.f;
          } else {                               // ck+1 still inside the 128-k A-tile
            const int ck1 = ck + 1;
            dnext = fp8_dec(sA[lastBuf][rt * 128 + (((ck1 >> 4) ^ (rt & 7)) << 4) + (ck1 & 15)]);
          }
        }
        if (icol < 1023) {
          float frac = COEF * acc[fn][reg];
          float ut = (icol == 1022) ? dui : 0.5f * (dui + dnext);
          float res = ut - frac;
          psum += res * res;
        }
      }
    }
  };

  stageA(0, 0);                            // prologue: A(it=0)
  for (int it = 0; it < 9; it++) {
    const bool ph1 = it < nkb1;
    const int ct = ph1 ? ct1 : ct2;
    const int kb = ph1 ? it : it - nkb1;
    // BARRIER A: compute(it-1) done (and phase-1 epilogue, if any) -> sB + sA[(it+1)&1] free
    asm volatile("" ::: "memory");
    __builtin_amdgcn_s_barrier();
    asm volatile("" ::: "memory");
    stageB(ct, kb);                                    // issue B(it) (1 load)
    if (it + 1 < 9) {
      const bool nph1 = (it + 1) < nkb1;
      const int nkb_ = nph1 ? it + 1 : it + 1 - nkb1;
      stageA((it + 1) & 1, nkb_);                      // issue A(it+1) (1 load, in flight)
      asm volatile("s_waitcnt vmcnt(1)" ::: "memory"); // A(it)+B(it) done; A(it+1) pending
    } else {
      asm volatile("s_waitcnt vmcnt(0)" ::: "memory"); // last iter: drain
    }
    // BARRIER B: tile resident for all waves
    __builtin_amdgcn_s_barrier();
    asm volatile("" ::: "memory");
    compute(it & 1);
    if (it == nkb1 - 1) {                  // end of phase 1: epilogue from sA[it&1]
      epilogue(ct1, it & 1);               // (safe: next stage into this buffer parity
      acc[0] = vzero; acc[1] = vzero;      //  happens only after the next barrier A)
    }
  }
  epilogue(ct2, 8 & 1);                    // phase 2 epilogue (last iter it=8 -> buf 0)

#pragma unroll
  for (int off = 32; off > 0; off >>= 1) psum += __shfl_down(psum, off, 64);
  if (lane == 0) wsum[w] = psum;

  // pre-reduce this block's 8-row slice of dpart/ppart (wave 0; any bijection works)
  float ds_ = 0.f, ps_ = 0.f;
  if (w == 0) {
    if (t < 8) { ds_ = dpart[bid * 8 + t]; ps_ = ppart[bid * 8 + t]; }
#pragma unroll
    for (int off = 4; off > 0; off >>= 1) {
      ds_ += __shfl_down(ds_, off, 64);
      ps_ += __shfl_down(ps_, off, 64);
    }
  }
  __syncthreads();
  if (t == 0) {
    float s = 0.f;
#pragma unroll
    for (int i = 0; i < 8; i++) s += wsum[i];
    gpart[bid] = s + ps_;
    gpart[1024 + bid] = ds_;
  }
}

// Single-block reduction of 2048 partials -> 3 outputs.
__global__ void finalize(const float* __restrict__ gpart, float* __restrict__ out) {
  const int t = threadIdx.x;    // 256 threads
  float ds = 0.f, ps = 0.f;
  for (int i = t; i < 1024; i += 256) { ps += gpart[i]; ds += gpart[1024 + i]; }

#pragma unroll
  for (int off = 32; off > 0; off >>= 1) {
    ds += __shfl_down(ds, off, 64);
    ps += __shfl_down(ps, off, 64);
  }
  __shared__ float sd[4], sp[4];
  const int lane = t & 63, w = t >> 6;
  if (lane == 0) { sd[w] = ds; sp[w] = ps; }
  __syncthreads();
  if (t == 0) {
    float data = (sd[0] + sd[1] + sd[2] + sd[3]) * INV_COUNT;
    float phys = (sp[0] + sp[1] + sp[2] + sp[3]) * INV_COUNT;
    out[0] = data + 0.1f * phys;
    out[1] = data;
    out[2] = phys;
  }
}

extern "C" void kernel_launch(void* const* d_in, const int* in_sizes, int n_in,
                              void* d_out, int out_size, void* d_ws, size_t ws_size,
                              hipStream_t stream) {
  const float* u_pred = (const float*)d_in[0];
  const float* u_true = (const float*)d_in[1];
  float* out = (float*)d_out;

  char* ws = (char*)d_ws;
  float* dpart = (float*)ws;                                    // 8192 floats (32 KiB)
  float* ppart = (float*)(ws + 32768);                          // 8192 floats (32 KiB)
  float* gpart = (float*)(ws + 65536);                          // 2048 floats (8 KiB)
  unsigned char* Mt8d = (unsigned char*)(ws + 131072);          // 8 tiles * 16 KiB = 128 KiB
  unsigned char* du8 = (unsigned char*)(ws + 131072 + 1048576); // 8192*1024 = 8 MiB

  prep<<<8320, 256, 0, stream>>>(u_pred, u_true, du8, Mt8d, dpart, ppart);
  gemm<<<1024, 512, 0, stream>>>(du8, Mt8d, gpart, dpart, ppart);
  finalize<<<1, 256, 0, stream>>>(gpart, out);
}

// Round 22
// 35.140 us; speedup vs baseline: 1.6472x; 1.2793x over previous
//
#include <hip/hip_runtime.h>
#include <hip/hip_bf16.h>

// B=32, T=256, N=1024 -> R = 8192 rows, K = 1023 (padded 1024)
// alpha=0.5, b[m] = 1/(sqrt(m+1)+sqrt(m)), coef = sqrt(1023)/Gamma(1.5)
#define COEF 36.090511f
#define INV_COUNT (1.0f / 8388608.0f)   // 1 / (32*256*1024)

typedef __attribute__((ext_vector_type(4))) float f32x4;
typedef __attribute__((ext_vector_type(2))) unsigned long long u64x2;

typedef const __attribute__((address_space(1))) unsigned int* gas_ptr;
typedef __attribute__((address_space(3))) unsigned int* las_ptr;

__device__ __forceinline__ void load_lds16(const void* g, void* l) {
  __builtin_amdgcn_global_load_lds((gas_ptr)g, (las_ptr)l, 16, 0, 0);
}

// manual OCP e4m3fn decode (bias 7): exact
__device__ __forceinline__ float fp8_dec(unsigned int v) {
  const unsigned e = (v >> 3) & 0xF, m = v & 7;
  const int mant = e ? (8 + (int)m) : (int)m;
  const int ee = e ? (int)e : 1;
  float f = (float)mant * __int_as_float((ee + 117) << 23);  // mant * 2^(ee-10)
  return (v & 0x80) ? -f : f;
}

// prep blocks 0..8191: du8 rows, XCD-aligned map r = (b&7)*1024 + (b>>3).
// blocks 8192..8319: Mt8d = dedup'd Toeplitz B (8 tiles of 16KB, d = cb-kb).
__global__ void prep(const float* __restrict__ up, const float* __restrict__ utr,
                     unsigned char* __restrict__ du8, unsigned char* __restrict__ Mt8d,
                     float* __restrict__ dpart, float* __restrict__ ppart) {
  const int t = threadIdx.x;      // 256 threads
  if (blockIdx.x >= 8192) {
    const int g = (blockIdx.x - 8192) * 1024 + t * 4;   // byte index into 128KB tile set
    const int d = g >> 14;            // tile 0..7
    const int rem = g & 16383;
    const int ip = rem >> 7;          // i' 0..127
    const int j0 = rem & 127;         // j' byte
    float v[4];
#pragma unroll
    for (int e = 0; e < 4; e++) {
      int m = d * 128 + ip - (j0 + e);
      v[e] = 0.f;
      if (m >= 0) { float fm_ = (float)m; v[e] = 1.0f / (sqrtf(fm_ + 1.f) + sqrtf(fm_)); }
    }
    int w_ = __builtin_amdgcn_cvt_pk_fp8_f32(v[0], v[1], 0, false);
    w_ = __builtin_amdgcn_cvt_pk_fp8_f32(v[2], v[3], w_, true);
    *(unsigned int*)(Mt8d + g) = (unsigned int)w_;
    return;
  }

  const int r = ((blockIdx.x & 7) << 10) | (blockIdx.x >> 3);   // XCD-aligned row
  const int j0 = t * 4;
  const float* rowp = up + (size_t)r * 1024;

  f32x4 a = *(const f32x4*)(rowp + j0);
  f32x4 b = *(const f32x4*)(utr + (size_t)r * 1024 + j0);

  float a4 = __shfl_down(a[0], 1, 64);
  if ((t & 63) == 63 && t < 255) a4 = rowp[j0 + 4];

  float d0 = a[1] - a[0];
  float d1 = a[2] - a[1];
  float d2 = a[3] - a[2];
  float d3 = (t < 255) ? (a4 - a[3]) : 0.f;   // du[1023] = 0 pad

  int w_ = __builtin_amdgcn_cvt_pk_fp8_f32(d0, d1, 0, false);
  w_ = __builtin_amdgcn_cvt_pk_fp8_f32(d2, d3, w_, true);
  *(unsigned int*)(du8 + (size_t)r * 1024 + j0) = (unsigned int)w_;

  float e0 = a[0] - b[0], e1 = a[1] - b[1], e2 = a[2] - b[2], e3 = a[3] - b[3];
  float dsum = e0 * e0 + e1 * e1 + e2 * e2 + e3 * e3;

#pragma unroll
  for (int off = 32; off > 0; off >>= 1) dsum += __shfl_down(dsum, off, 64);
  __shared__ float ws4[4];
  const int lane = t & 63, w = t >> 6;
  if (lane == 0) ws4[w] = dsum;
  __syncthreads();
  if (t == 0) {
    dpart[r] = ws4[0] + ws4[1] + ws4[2] + ws4[3];
    ppart[r] = d0 * d0;   // physics residual at n=0: u_t = du[r,0], frac_lap[0] = 0
  }
}

// Y[r,i] = sum_j du[r,j] * b[i-j]; fused epilogue: resid = u_t - COEF*Y, psum += resid^2.
// fp8 GEMM: 64x128 tile, BK=128 bytes, 8 waves (32x32 wave tile), 1024 blocks -> up to
// 32 waves/CU. LDS 32KB: sA double-buffered + sB SINGLE (barrier A orders the
// overwrite; issue-order vmcnt(1) keeps A-prefetch in flight while draining B(k)+A(k)).
// XOR quad-swizzle, XCD map (bid&7), triangular cb uniform under 4-packs both orders.
__launch_bounds__(512, 8)
__global__ void gemm(const unsigned char* __restrict__ du8,
                     const unsigned char* __restrict__ Mt8d,
                     float* __restrict__ gpart,
                     const float* __restrict__ dpart, const float* __restrict__ ppart) {
  __shared__ unsigned char sA[2][8192];    // [64 rows][128 k-bytes], quad-swizzled
  __shared__ unsigned char sB[16384];      // [128 cols][128 k-bytes], single-buffered
  __shared__ float wsum[8];

  const int t = threadIdx.x;      // 512 threads = 8 waves
  const int w = t >> 6;
  const int lane = t & 63;

  const int bid = blockIdx.x;      // 0..1023
  const int xcd = bid & 7;
  const int local = bid >> 3;      // 0..127
  const int e = local & 1;
  const int j = local >> 1;        // 0..63
  const int h = (j < 32) ? (j & 7) : 7 - (j & 7);
  const int cb = e ? 7 - h : h;    // consecutive pairs AND +-32 j-pairs sum to 7
  const int r16 = (((j >> 3) & 3) << 2) | (((j >> 5) & 1) << 1) | e;   // bijective
  const int rb = xcd * 16 + r16;   // 0..127 (64-row tiles); XCD x owns rows [x*1024,+1024)
  const int row0 = rb * 64;
  const int col0 = cb * 128;
  const int nkb = cb + 1;          // K-blocks of 128 bytes (triangular skip)

  const f32x4 vzero = {0.f, 0.f, 0.f, 0.f};
  f32x4 acc[2][2];
#pragma unroll
  for (int i = 0; i < 2; i++)
#pragma unroll
    for (int jj = 0; jj < 2; jj++) acc[i][jj] = vzero;

  // staging: 512 threads x 16B = 8KB/call -> 2 calls per 16KB tile.
  // thread t covers (row = t>>3 within call-half, phys quad = t&7); src quad = phys ^ (row&7)
  const int srow = t >> 3;                            // 0..63
  const int sq = ((t & 7) ^ (srow & 7)) * 16;         // pre-swizzled source byte col
  const unsigned char* gA0 = du8 + (size_t)(row0 + srow) * 1024 + sq;
  const unsigned char* gB0 = Mt8d + srow * 128 + sq;  // + d*16384 per iter

  auto stageA = [&](int buf, int kb) {                // 1 load: 64x128 = 8KB
    load_lds16(gA0 + kb * 128, (void*)&sA[buf][t * 16]);
  };
  auto stageB = [&](int kb) {                         // 2 loads: 128x128 = 16KB
    const size_t doff = (size_t)(cb - kb) * 16384;
#pragma unroll
    for (int l = 0; l < 2; l++)
      load_lds16(gB0 + doff + l * 64 * 128, (void*)&sB[l * 8192 + t * 16]);
  };

  const int wm = w >> 2, wn = w & 3;     // wave tile: rows wm*32, cols wn*32
  const int frow = lane & 15;
  const int g4 = lane >> 4;              // lane's k-owner group 0..3

  auto compute = [&](int buf) {
#pragma unroll
    for (int p = 0; p < 2; p++) {
      const int lq = g4 * 2 + p;               // logical quad
      const int ph = lq ^ (frow & 7);          // physical quad (swizzle)
      u64x2 aV[2], bV[2];
#pragma unroll
      for (int fm = 0; fm < 2; fm++)
        aV[fm] = *(const u64x2*)&sA[buf][(wm * 32 + fm * 16 + frow) * 128 + ph * 16];
#pragma unroll
      for (int fn = 0; fn < 2; fn++)
        bV[fn] = *(const u64x2*)&sB[(wn * 32 + fn * 16 + frow) * 128 + ph * 16];
#pragma unroll
      for (int fm = 0; fm < 2; fm++)
#pragma unroll
        for (int fn = 0; fn < 2; fn++) {
          acc[fm][fn] = __builtin_amdgcn_mfma_f32_16x16x32_fp8_fp8(
              (long long)aV[fm].x, (long long)bV[fn].x, acc[fm][fn], 0, 0, 0);
          acc[fm][fn] = __builtin_amdgcn_mfma_f32_16x16x32_fp8_fp8(
              (long long)aV[fm].y, (long long)bV[fn].y, acc[fm][fn], 0, 0, 0);
        }
    }
  };

  stageA(0, 0);
  for (int kb = 0; kb < nkb; kb++) {
    asm volatile("" ::: "memory");
    __builtin_amdgcn_s_barrier();                      // BARRIER A: sB + buf free
    asm volatile("" ::: "memory");
    stageB(kb);                                        // issue B(k) FIRST (older)
    if (kb + 1 < nkb) {
      stageA((kb + 1) & 1, kb + 1);                    // then A(k+1) (younger, stays in flight)
      asm volatile("s_waitcnt vmcnt(1)" ::: "memory"); // A(k), B(k) complete; A(k+1) pending
    } else {
      asm volatile("s_waitcnt vmcnt(0)" ::: "memory"); // last tile: drain
    }
    __builtin_amdgcn_s_barrier();                      // BARRIER B: tile resident
    asm volatile("" ::: "memory");
    compute(kb & 1);
  }

  // fused epilogue: C/D layout col = lane&15, row = (lane>>4)*4 + reg  [HW-verified].
  // du bytes from LAST A-tile in LDS: byte (rt,c) at rt*128 + ((c>>4)^(rt&7))*16 + (c&15).
  // Neighbor (c+1) via __shfl_down within 16-lane group; frow==15 reads explicitly.
  const int lastBuf = (nkb - 1) & 1;
  float psum = 0.f;
#pragma unroll
  for (int fm = 0; fm < 2; fm++) {
#pragma unroll
    for (int fn = 0; fn < 2; fn++) {
      const int c = wn * 32 + fn * 16 + frow;    // col within tile
      const int icol = col0 + c;                 // du index i; output position n = i+1
#pragma unroll
      for (int reg = 0; reg < 4; reg++) {
        const int rt = wm * 32 + fm * 16 + g4 * 4 + reg;   // row within tile (0..63)
        float dui = fp8_dec(sA[lastBuf][rt * 128 + (((c >> 4) ^ (rt & 7)) << 4) + (c & 15)]);
        float dnext = __shfl_down(dui, 1, 64);             // dui of (rt, c+1) for frow<15
        if (frow == 15) {
          if (c == 127) {                                  // tile edge: global byte (cb<7)
            dnext = (icol < 1022) ? fp8_dec(du8[(size_t)(row0 + rt) * 1024 + icol + 1]) : 0.f;
          } else {
            const int c1 = c + 1;
            dnext = fp8_dec(sA[lastBuf][rt * 128 + (((c1 >> 4) ^ (rt & 7)) << 4) + (c1 & 15)]);
          }
        }
        if (icol < 1023) {
          float frac = COEF * acc[fm][fn][reg];
          float ut = (icol == 1022) ? dui : 0.5f * (dui + dnext);
          float res = ut - frac;
          psum += res * res;
        }
      }
    }
  }

#pragma unroll
  for (int off = 32; off > 0; off >>= 1) psum += __shfl_down(psum, off, 64);
  if (lane == 0) wsum[w] = psum;

  // pre-reduce this block's 8-row slice of dpart/ppart (wave 0)
  float ds_ = 0.f, ps_ = 0.f;
  if (w == 0) {
    if (t < 8) { ds_ = dpart[bid * 8 + t]; ps_ = ppart[bid * 8 + t]; }
#pragma unroll
    for (int off = 4; off > 0; off >>= 1) {
      ds_ += __shfl_down(ds_, off, 64);
      ps_ += __shfl_down(ps_, off, 64);
    }
  }
  __syncthreads();
  if (t == 0) {
    float s = 0.f;
#pragma unroll
    for (int i = 0; i < 8; i++) s += wsum[i];
    gpart[bid] = s + ps_;
    gpart[1024 + bid] = ds_;
  }
}

// Single-block reduction of 2048 partials -> 3 outputs.
__global__ void finalize(const float* __restrict__ gpart, float* __restrict__ out) {
  const int t = threadIdx.x;    // 256 threads
  float ds = 0.f, ps = 0.f;
  for (int i = t; i < 1024; i += 256) { ps += gpart[i]; ds += gpart[1024 + i]; }

#pragma unroll
  for (int off = 32; off > 0; off >>= 1) {
    ds += __shfl_down(ds, off, 64);
    ps += __shfl_down(ps, off, 64);
  }
  __shared__ float sd[4], sp[4];
  const int lane = t & 63, w = t >> 6;
  if (lane == 0) { sd[w] = ds; sp[w] = ps; }
  __syncthreads();
  if (t == 0) {
    float data = (sd[0] + sd[1] + sd[2] + sd[3]) * INV_COUNT;
    float phys = (sp[0] + sp[1] + sp[2] + sp[3]) * INV_COUNT;
    out[0] = data + 0.1f * phys;
    out[1] = data;
    out[2] = phys;
  }
}

extern "C" void kernel_launch(void* const* d_in, const int* in_sizes, int n_in,
                              void* d_out, int out_size, void* d_ws, size_t ws_size,
                              hipStream_t stream) {
  const float* u_pred = (const float*)d_in[0];
  const float* u_true = (const float*)d_in[1];
  float* out = (float*)d_out;

  char* ws = (char*)d_ws;
  float* dpart = (float*)ws;                                    // 8192 floats (32 KiB)
  float* ppart = (float*)(ws + 32768);                          // 8192 floats (32 KiB)
  float* gpart = (float*)(ws + 65536);                          // 2048 floats (8 KiB)
  unsigned char* Mt8d = (unsigned char*)(ws + 131072);          // 8 tiles * 16 KiB = 128 KiB
  unsigned char* du8 = (unsigned char*)(ws + 131072 + 1048576); // 8192*1024 = 8 MiB

  prep<<<8320, 256, 0, stream>>>(u_pred, u_true, du8, Mt8d, dpart, ppart);
  gemm<<<1024, 512, 0, stream>>>(du8, Mt8d, gpart, dpart, ppart);
  finalize<<<1, 256, 0, stream>>>(gpart, out);
}